// Round 1
// baseline (301.246 us; speedup 1.0000x reference)
//
#include <hip/hip_runtime.h>

namespace {

constexpr int D    = 128;   // feature dim
constexpr int WFm  = 80;    // feature map width
constexpr int HFm  = 60;    // feature map height
constexpr int NPIX = WFm * HFm;
constexpr int NKPT = 1024;
constexpr int LE   = 128;   // epipolar samples
constexpr int KW   = 256;   // window samples (16x16)

__device__ __forceinline__ float wave_sum64(float v) {
#pragma unroll
  for (int m = 32; m > 0; m >>= 1) v += __shfl_xor(v, m, 64);
  return v;
}

// ---------------------------------------------------------------------------
// prep: for each image/map, produce
//   xfT[b][pix][d]  (pixel-major transpose of raw features)
//   sc[b][pix] = T / max(||xf[b,:,pix]||, 1e-12)
// LDS-tiled transpose, 64 pixels x 128 d per block.
// ---------------------------------------------------------------------------
__global__ __launch_bounds__(256) void prep_kernel(
    const float* __restrict__ xf1, const float* __restrict__ xf2,
    const int* __restrict__ epoch,
    float* __restrict__ xf1T, float* __restrict__ xf2T,
    float* __restrict__ sc1, float* __restrict__ sc2) {
  __shared__ float tile[64 * 129];  // +1 pad breaks bank conflicts

  const int bi   = blockIdx.x;
  const int img  = bi / 150;
  const int rem  = bi % 150;
  const int b    = rem / 75;
  const int p0   = (rem % 75) * 64;
  const int tid  = threadIdx.x;

  const float* src  = img ? xf2 : xf1;
  float* dstT       = img ? xf2T : xf1T;
  float* dstS       = img ? sc2 : sc1;
  const float T     = fminf(1.0f + (float)(*epoch), 50.0f);

  const int dc = tid >> 6;       // 0..3
  const int px = tid & 63;       // 0..63
#pragma unroll 4
  for (int it = 0; it < 32; ++it) {
    int d = it * 4 + dc;
    tile[px * 129 + d] = src[((size_t)(b * D + d)) * NPIX + p0 + px];
  }
  __syncthreads();

  if (tid < 64) {
    float s = 0.f;
#pragma unroll 8
    for (int d = 0; d < D; ++d) {
      float v = tile[tid * 129 + d];
      s += v * v;
    }
    dstS[b * NPIX + p0 + tid] = T / fmaxf(sqrtf(s), 1e-12f);
  }

#pragma unroll 4
  for (int it = 0; it < 32; ++it) {
    int idx = it * 256 + tid;
    int lpx = idx >> 7;
    int d   = idx & 127;
    dstT[((size_t)(b * NPIX + p0 + lpx)) * D + d] = tile[lpx * 129 + d];
  }
}

// ---------------------------------------------------------------------------
// main: one block per (dir, b, n). 256 threads = 4 waves.
// out layout (floats):
//   [0     .. 4096 ) coord1            (b,n,2)
//   [4096  .. 8192 ) coord2
//   [8192  ..12288 ) feat1w_corloc
//   [12288 ..16384 ) feat2w_corloc
//   [16384 ..20480 ) feat1c_corloc_org (denormed epi mean, dir0)
//   [20480 ..24576 ) c2_org_n          (raw normalized epi mean, dir1)
//   [24576 ..26624 ) f1w_std
//   [26624 ..28672 ) f2w_std
//   [28672 ..30720 ) valid1 (1.0/0.0)
//   [30720 ..32768 ) valid2
// ---------------------------------------------------------------------------
__global__ __launch_bounds__(256) void line2win_kernel(
    const float* __restrict__ xf1T, const float* __restrict__ xf2T,
    const float* __restrict__ sc1, const float* __restrict__ sc2,
    const float* __restrict__ F1, const float* __restrict__ F2,
    const float* __restrict__ c1n, const float* __restrict__ c2n,
    float* __restrict__ out) {
  __shared__ float featSh[D];
  __shared__ float corrSh[KW];
  __shared__ float rA[256], rB[256], rC[256], rD[256], rE[256];

  const int tid  = threadIdx.x;
  const int lane = tid & 63;
  const int wid  = tid >> 6;
  const int bid  = blockIdx.x;
  const int dir  = bid >> 11;         // 0: img1->2, 1: img2->1
  const int b    = (bid >> 10) & 1;
  const int n    = bid & 1023;
  const int kix  = b * NKPT + n;

  const float* srcT = dir ? xf2T : xf1T;  // descriptor source (raw)
  const float* tgtT = dir ? xf1T : xf2T;  // correlation target (raw)
  const float* tsc  = dir ? sc1 : sc2;    // target scale = T/norm
  const float* Fm   = (dir ? F2 : F1) + b * 9;
  const float* cn   = (dir ? c2n : c1n) + kix * 2;

  const float cnx_in = cn[0], cny_in = cn[1];
  const float px = (cnx_in + 1.f) * 319.5f;   // denorm to 640-wide image
  const float py = (cny_in + 1.f) * 239.5f;   // denorm to 480-high image

  // epipolar line coefficients: [a,b,c] = F @ [px,py,1]
  const float la = Fm[0] * px + Fm[1] * py + Fm[2];
  const float lb = Fm[3] * px + Fm[4] * py + Fm[5];
  const float lc = Fm[6] * px + Fm[7] * py + Fm[8];
  const float eps = 1e-8f;
  const bool  use_x = fabsf(lb) >= fabsf(la);
  const float bden  = (fabsf(lb) < eps) ? eps : lb;
  const float aden  = (fabsf(la) < eps) ? eps : la;
  const bool  degen = (fabsf(la) < eps) && (fabsf(lb) < eps);

  // ---- phase 1: descriptor = l2norm(bilinear_sample(raw src map)) ----
  const size_t srcBase = (size_t)b * NPIX * D;
  float fval = 0.f;
  {
    float xf = (cnx_in + 1.f) * 39.5f;   // feature-map coords (80x60)
    float yf = (cny_in + 1.f) * 29.5f;
    float x0 = floorf(xf), y0 = floorf(yf);
    float wx1 = xf - x0, wx0 = 1.f - wx1;
    float wy1 = yf - y0, wy0 = 1.f - wy1;
    if (tid < D) {
#pragma unroll
      for (int cyi = 0; cyi < 2; ++cyi)
#pragma unroll
        for (int cxi = 0; cxi < 2; ++cxi) {
          float xi = x0 + (float)cxi, yi = y0 + (float)cyi;
          bool inb = (xi >= 0.f) && (xi <= (float)(WFm - 1)) &&
                     (yi >= 0.f) && (yi <= (float)(HFm - 1));
          float w = (cxi ? wx1 : wx0) * (cyi ? wy1 : wy0);
          if (inb && w != 0.f) {
            int p = (int)yi * WFm + (int)xi;
            fval += w * srcT[srcBase + (size_t)p * D + tid];
          }
        }
    }
  }
  rA[tid] = (tid < D) ? fval * fval : 0.f;
  __syncthreads();
  for (int s = 128; s > 0; s >>= 1) {
    if (tid < s) rA[tid] += rA[tid + s];
    __syncthreads();
  }
  const float inv = 1.f / fmaxf(sqrtf(rA[0]), 1e-12f);
  __syncthreads();
  if (tid < D) featSh[tid] = fval * inv;
  __syncthreads();
  const float fA = featSh[2 * lane];
  const float fB = featSh[2 * lane + 1];

  // per-lane partial of  sum_c w_c*inb_c*scale[p_c]*dot(feat, tgt[p_c])
  const size_t tb = (size_t)b * NPIX * D;
  auto cdot = [&](float cnx, float cny) -> float {
    float xf = (cnx + 1.f) * 39.5f;
    float yf = (cny + 1.f) * 29.5f;
    float x0 = floorf(xf), y0 = floorf(yf);
    float wx1 = xf - x0, wx0 = 1.f - wx1;
    float wy1 = yf - y0, wy0 = 1.f - wy1;
    float acc = 0.f;
#pragma unroll
    for (int cyi = 0; cyi < 2; ++cyi)
#pragma unroll
      for (int cxi = 0; cxi < 2; ++cxi) {
        float xi = x0 + (float)cxi, yi = y0 + (float)cyi;
        bool inb = (xi >= 0.f) && (xi <= (float)(WFm - 1)) &&
                   (yi >= 0.f) && (yi <= (float)(HFm - 1));
        float w = (cxi ? wx1 : wx0) * (cyi ? wy1 : wy0);
        if (inb && w != 0.f) {  // wave-uniform branch
          int p = (int)yi * WFm + (int)xi;
          float coef = w * tsc[b * NPIX + p];
          const float2 m =
              *reinterpret_cast<const float2*>(tgtT + tb + (size_t)p * D + 2 * lane);
          acc += coef * (fA * m.x + fB * m.y);
        }
      }
    return acc;
  };

  // ---- phase 2: epipolar correlations (wave-per-sample) ----
  for (int j = wid; j < LE; j += 4) {
    float t = (float)j / 127.0f;
    float xs, ys;
    if (use_x) { xs = t * 639.f; ys = -(la * xs + lc) / bden; }
    else       { ys = t * 479.f; xs = -(lb * ys + lc) / aden; }
    float cx = xs / 319.5f - 1.f;
    float cy = ys / 239.5f - 1.f;
    float acc = wave_sum64(cdot(cx, cy));
    if (lane == 0) corrSh[j] = acc;
  }
  __syncthreads();

  // ---- phase 3: masked softmax over L, mean, valid ----
  float lgt = -3.0e38f, cxj = 0.f, cyj = 0.f, vj = 0.f;
  if (tid < LE) {
    float t = (float)tid / 127.0f;
    float xs, ys;
    if (use_x) { xs = t * 639.f; ys = -(la * xs + lc) / bden; }
    else       { ys = t * 479.f; xs = -(lb * ys + lc) / aden; }
    bool valid = (xs >= 0.f) && (xs <= 639.f) && (ys >= 0.f) && (ys <= 479.f) && !degen;
    cxj = xs / 319.5f - 1.f;
    cyj = ys / 239.5f - 1.f;
    vj  = valid ? 1.f : 0.f;
    lgt = valid ? corrSh[tid] : -1e9f;
  }
  rA[tid] = lgt;
  __syncthreads();
  for (int s = 128; s > 0; s >>= 1) {
    if (tid < s) rA[tid] = fmaxf(rA[tid], rA[tid + s]);
    __syncthreads();
  }
  const float mx = rA[0];
  __syncthreads();
  const float e = (tid < LE) ? expf(lgt - mx) : 0.f;
  rA[tid] = e;
  rB[tid] = e * cxj;
  rC[tid] = e * cyj;
  rD[tid] = vj;
  __syncthreads();
  for (int s = 128; s > 0; s >>= 1) {
    if (tid < s) {
      rA[tid] += rA[tid + s];
      rB[tid] += rB[tid + s];
      rC[tid] += rC[tid + s];
      rD[tid] += rD[tid + s];
    }
    __syncthreads();
  }
  const float sumE  = rA[0];
  const float meanx = rB[0] / sumE;
  const float meany = rC[0] / sumE;
  const bool  anyv  = rD[0] > 0.f;
  const float ccx = fminf(fmaxf(meanx, -0.875f), 0.875f);  // clip to +-(1-WINDOW)
  const float ccy = fminf(fmaxf(meany, -0.875f), 0.875f);

  if (tid == 0) {
    float* o_coord = out + dir * 4096 + kix * 2;  // denormed input coords
    o_coord[0] = px;
    o_coord[1] = py;
    float* o_org = out + 16384 + dir * 4096 + kix * 2;
    if (dir == 0) {  // feat1c_corloc_org = denorm(mean)
      o_org[0] = (meanx + 1.f) * 319.5f;
      o_org[1] = (meany + 1.f) * 239.5f;
    } else {         // c2_org_n raw normalized
      o_org[0] = meanx;
      o_org[1] = meany;
    }
    out[28672 + dir * 2048 + kix] = anyv ? 1.f : 0.f;
  }

  // ---- phase 4: window correlations (wave-per-sample, 256 samples) ----
  const float offStep = 0.25f / 15.f;
  for (int k = wid; k < KW; k += 4) {
    float ox = -0.125f + (float)(k & 15) * offStep;
    float oy = -0.125f + (float)(k >> 4) * offStep;
    float acc = wave_sum64(cdot(ccx + ox, ccy + oy));
    if (lane == 0) corrSh[k] = acc;
  }
  __syncthreads();

  // ---- phase 5: softmax over 256 window samples, mean + std ----
  const float ox = -0.125f + (float)(tid & 15) * offStep;
  const float oy = -0.125f + (float)(tid >> 4) * offStep;
  const float kcx = ccx + ox;
  const float kcy = ccy + oy;
  const float lg2 = corrSh[tid];
  rA[tid] = lg2;
  __syncthreads();
  for (int s = 128; s > 0; s >>= 1) {
    if (tid < s) rA[tid] = fmaxf(rA[tid], rA[tid + s]);
    __syncthreads();
  }
  const float mx2 = rA[0];
  __syncthreads();
  const float e2 = expf(lg2 - mx2);
  rA[tid] = e2;
  rB[tid] = e2 * kcx;
  rC[tid] = e2 * kcy;
  rD[tid] = e2 * kcx * kcx;
  rE[tid] = e2 * kcy * kcy;
  __syncthreads();
  for (int s = 128; s > 0; s >>= 1) {
    if (tid < s) {
      rA[tid] += rA[tid + s];
      rB[tid] += rB[tid + s];
      rC[tid] += rC[tid + s];
      rD[tid] += rD[tid + s];
      rE[tid] += rE[tid + s];
    }
    __syncthreads();
  }
  if (tid == 0) {
    float sE  = rA[0];
    float mwx = rB[0] / sE;
    float mwy = rC[0] / sE;
    float vx  = fmaxf(rD[0] / sE - mwx * mwx, 0.f);
    float vy  = fmaxf(rE[0] / sE - mwy * mwy, 0.f);
    float stdv = sqrtf(vx + vy + 1e-12f);
    float* o_w = out + 8192 + dir * 4096 + kix * 2;
    o_w[0] = (mwx + 1.f) * 319.5f;   // denorm window mean
    o_w[1] = (mwy + 1.f) * 239.5f;
    out[24576 + dir * 2048 + kix] = stdv;
  }
}

}  // namespace

extern "C" void kernel_launch(void* const* d_in, const int* in_sizes, int n_in,
                              void* d_out, int out_size, void* d_ws, size_t ws_size,
                              hipStream_t stream) {
  (void)in_sizes; (void)n_in; (void)out_size; (void)ws_size;
  const float* xf1 = (const float*)d_in[0];
  const float* xf2 = (const float*)d_in[1];
  const float* F1  = (const float*)d_in[2];
  const float* F2  = (const float*)d_in[3];
  const float* c1n = (const float*)d_in[4];
  const float* c2n = (const float*)d_in[5];
  const int* epoch = (const int*)d_in[6];

  float* ws   = (float*)d_ws;
  float* xf1T = ws;                               // 2*4800*128
  float* xf2T = ws + (size_t)2 * NPIX * D;        // 2*4800*128
  float* sc1  = ws + (size_t)4 * NPIX * D;        // 2*4800
  float* sc2  = sc1 + 2 * NPIX;                   // 2*4800
  float* out  = (float*)d_out;

  hipLaunchKernelGGL(prep_kernel, dim3(300), dim3(256), 0, stream,
                     xf1, xf2, epoch, xf1T, xf2T, sc1, sc2);
  hipLaunchKernelGGL(line2win_kernel, dim3(4096), dim3(256), 0, stream,
                     xf1T, xf2T, sc1, sc2, F1, F2, c1n, c2n, out);
}

// Round 2
// 90.159 us; speedup vs baseline: 3.3413x; 3.3413x over previous
//
#include <hip/hip_runtime.h>

namespace {

constexpr int D    = 128;   // feature dim
constexpr int WFm  = 80;    // feature map width
constexpr int HFm  = 60;    // feature map height
constexpr int NPIX = WFm * HFm;
constexpr int NKPT = 1024;
constexpr int LE   = 128;   // epipolar samples
constexpr int LCX  = 12;    // window lattice cols
constexpr int LCY  = 10;    // window lattice rows
constexpr int NLAT = LCX * LCY;

__device__ __forceinline__ float wsum(float v) {
#pragma unroll
  for (int m = 32; m; m >>= 1) v += __shfl_xor(v, m, 64);
  return v;
}
__device__ __forceinline__ float wmax(float v) {
#pragma unroll
  for (int m = 32; m; m >>= 1) v = fmaxf(v, __shfl_xor(v, m, 64));
  return v;
}

// ---------------------------------------------------------------------------
// prep: xfT[b][pix][d] transpose + sc[b][pix] = T/max(||xf[:,pix]||,1e-12)
// ---------------------------------------------------------------------------
__global__ __launch_bounds__(256) void prep_kernel(
    const float* __restrict__ xf1, const float* __restrict__ xf2,
    const int* __restrict__ epoch,
    float* __restrict__ xf1T, float* __restrict__ xf2T,
    float* __restrict__ sc1, float* __restrict__ sc2) {
  __shared__ float tile[64 * 129];

  const int bi   = blockIdx.x;
  const int img  = bi / 150;
  const int rem  = bi % 150;
  const int b    = rem / 75;
  const int p0   = (rem % 75) * 64;
  const int tid  = threadIdx.x;

  const float* src  = img ? xf2 : xf1;
  float* dstT       = img ? xf2T : xf1T;
  float* dstS       = img ? sc2 : sc1;
  const float T     = fminf(1.0f + (float)(*epoch), 50.0f);

  const int dc = tid >> 6;
  const int px = tid & 63;
#pragma unroll 4
  for (int it = 0; it < 32; ++it) {
    int d = it * 4 + dc;
    tile[px * 129 + d] = src[((size_t)(b * D + d)) * NPIX + p0 + px];
  }
  __syncthreads();

  if (tid < 64) {
    float s = 0.f;
#pragma unroll 8
    for (int d = 0; d < D; ++d) {
      float v = tile[tid * 129 + d];
      s += v * v;
    }
    dstS[b * NPIX + p0 + tid] = T / fmaxf(sqrtf(s), 1e-12f);
  }

#pragma unroll 4
  for (int it = 0; it < 32; ++it) {
    int idx = it * 256 + tid;
    int lpx = idx >> 7;
    int d   = idx & 127;
    dstT[((size_t)(b * NPIX + p0 + lpx)) * D + d] = tile[lpx * 129 + d];
  }
}

// ---------------------------------------------------------------------------
// main: one block per (dir, b, n). 256 threads = 4 waves.
// out layout (floats): see round-0 comment (unchanged).
// ---------------------------------------------------------------------------
__global__ __launch_bounds__(256) void line2win_kernel(
    const float* __restrict__ xf1T, const float* __restrict__ xf2T,
    const float* __restrict__ sc1, const float* __restrict__ sc2,
    const float* __restrict__ F1, const float* __restrict__ F2,
    const float* __restrict__ c1n, const float* __restrict__ c2n,
    float* __restrict__ out) {
  __shared__ __align__(16) float featSh[D];
  __shared__ float dm[NLAT];
  __shared__ float pN[4], pM1[4], pS1[4][4], pM2[4], pS2[5][4];

  const int tid  = threadIdx.x;
  const int lane = tid & 63;
  const int wid  = tid >> 6;
  const int bid  = blockIdx.x;
  const int dir  = bid >> 11;
  const int b    = (bid >> 10) & 1;
  const int n    = bid & 1023;
  const int kix  = b * NKPT + n;

  const float* srcT = dir ? xf2T : xf1T;
  const float* tgtT = dir ? xf1T : xf2T;
  const float* tsc  = dir ? sc1 : sc2;
  const float* Fm   = (dir ? F2 : F1) + b * 9;
  const float* cn   = (dir ? c2n : c1n) + kix * 2;

  const float cnx_in = cn[0], cny_in = cn[1];
  const float px = (cnx_in + 1.f) * 319.5f;
  const float py = (cny_in + 1.f) * 239.5f;

  const float la = Fm[0] * px + Fm[1] * py + Fm[2];
  const float lb = Fm[3] * px + Fm[4] * py + Fm[5];
  const float lc = Fm[6] * px + Fm[7] * py + Fm[8];
  const float eps = 1e-8f;
  const bool  use_x = fabsf(lb) >= fabsf(la);
  const float bden  = (fabsf(lb) < eps) ? eps : lb;
  const float aden  = (fabsf(la) < eps) ? eps : la;
  const bool  degen = (fabsf(la) < eps) && (fabsf(lb) < eps);

  // ---- phase 1: descriptor = l2norm(bilinear_sample(raw src map)) ----
  const size_t srcBase = (size_t)b * NPIX * D;
  const size_t tb = (size_t)b * NPIX * D;
  float fval = 0.f;
  {
    float xf = (cnx_in + 1.f) * 39.5f;
    float yf = (cny_in + 1.f) * 29.5f;
    float x0 = floorf(xf), y0 = floorf(yf);
    float wx1 = xf - x0, wx0 = 1.f - wx1;
    float wy1 = yf - y0, wy0 = 1.f - wy1;
    if (tid < D) {
#pragma unroll
      for (int cyi = 0; cyi < 2; ++cyi)
#pragma unroll
        for (int cxi = 0; cxi < 2; ++cxi) {
          float xi = x0 + (float)cxi, yi = y0 + (float)cyi;
          bool inb = (xi >= 0.f) && (xi <= (float)(WFm - 1)) &&
                     (yi >= 0.f) && (yi <= (float)(HFm - 1));
          float w = (cxi ? wx1 : wx0) * (cyi ? wy1 : wy0);
          if (inb && w != 0.f) {
            int p = (int)yi * WFm + (int)xi;
            fval += w * srcT[srcBase + (size_t)p * D + tid];
          }
        }
    }
  }
  float nv = (tid < D) ? fval * fval : 0.f;
  nv = wsum(nv);
  if (lane == 0) pN[wid] = nv;
  __syncthreads();
  const float inv = 1.f / fmaxf(sqrtf(pN[0] + pN[1] + pN[2] + pN[3]), 1e-12f);
  if (tid < D) featSh[tid] = fval * inv;
  __syncthreads();

  // ---- phase 2: epipolar — thread pair per sample, 2 corners each ----
  const int j    = tid >> 1;
  const int half = tid & 1;
  float tpar = (float)j / 127.0f;
  float xs, ys;
  if (use_x) { xs = tpar * 639.f; ys = -(la * xs + lc) / bden; }
  else       { ys = tpar * 479.f; xs = -(lb * ys + lc) / aden; }
  const bool validS = (xs >= 0.f) && (xs <= 639.f) && (ys >= 0.f) && (ys <= 479.f) && !degen;
  const float cx = xs / 319.5f - 1.f;
  const float cy = ys / 239.5f - 1.f;

  float corr;
  {
    float xff = (cx + 1.f) * 39.5f;
    float yff = (cy + 1.f) * 29.5f;
    float x0f = floorf(fminf(fmaxf(xff, -4.f), 84.f));
    float y0f = floorf(fminf(fmaxf(yff, -4.f), 64.f));
    int x0i = (int)x0f, y0i = (int)y0f;
    float wx1 = xff - x0f, wx0 = 1.f - wx1;
    float wy1 = yff - y0f;
    float wyh = half ? wy1 : (1.f - wy1);
    int  yi  = y0i + half;
    bool yin = (yi >= 0) && (yi <= HFm - 1);
    int  yc  = min(max(yi, 0), HFm - 1);
    int  xA  = x0i, xB = x0i + 1;
    bool ain = yin && (xA >= 0) && (xA <= WFm - 1);
    bool bin2 = yin && (xB >= 0) && (xB <= WFm - 1);
    int  pA  = yc * WFm + min(max(xA, 0), WFm - 1);
    int  pB  = yc * WFm + min(max(xB, 0), WFm - 1);
    float cfA = ain  ? wx0 * wyh * tsc[b * NPIX + pA] : 0.f;
    float cfB = bin2 ? wx1 * wyh * tsc[b * NPIX + pB] : 0.f;
    float accA = 0.f, accB = 0.f;
    if (cfA != 0.f || cfB != 0.f) {
      const float4* mA = reinterpret_cast<const float4*>(tgtT + tb + (size_t)pA * D);
      const float4* mB = reinterpret_cast<const float4*>(tgtT + tb + (size_t)pB * D);
      const float4* fS = reinterpret_cast<const float4*>(featSh);
#pragma unroll 8
      for (int c = 0; c < 32; ++c) {
        float4 f = fS[c];
        float4 a = mA[c];
        float4 v = mB[c];
        accA += f.x * a.x + f.y * a.y + f.z * a.z + f.w * a.w;
        accB += f.x * v.x + f.y * v.y + f.z * v.z + f.w * v.w;
      }
    }
    float part = cfA * accA + cfB * accB;
    corr = part + __shfl_xor(part, 1, 64);
  }

  // ---- phase 3: masked softmax over L (pair-duplicated; ratios cancel) ----
  float lgt = validS ? corr : -1e9f;
  float mxw = wmax(lgt);
  if (lane == 0) pM1[wid] = mxw;
  __syncthreads();
  const float mx = fmaxf(fmaxf(pM1[0], pM1[1]), fmaxf(pM1[2], pM1[3]));
  const float e  = expf(lgt - mx);
  float s0 = wsum(e);
  float s1 = wsum(e * cx);
  float s2 = wsum(e * cy);
  float s3 = wsum(validS ? 1.f : 0.f);
  if (lane == 0) { pS1[0][wid] = s0; pS1[1][wid] = s1; pS1[2][wid] = s2; pS1[3][wid] = s3; }
  __syncthreads();
  const float sumE = pS1[0][0] + pS1[0][1] + pS1[0][2] + pS1[0][3];
  const float sumX = pS1[1][0] + pS1[1][1] + pS1[1][2] + pS1[1][3];
  const float sumY = pS1[2][0] + pS1[2][1] + pS1[2][2] + pS1[2][3];
  const float sumV = pS1[3][0] + pS1[3][1] + pS1[3][2] + pS1[3][3];
  const float meanx = sumX / sumE;
  const float meany = sumY / sumE;
  const bool  anyv  = sumV > 0.f;
  const float ccx = fminf(fmaxf(meanx, -0.875f), 0.875f);
  const float ccy = fminf(fmaxf(meany, -0.875f), 0.875f);

  if (tid == 0) {
    float* o_coord = out + dir * 4096 + kix * 2;
    o_coord[0] = px;
    o_coord[1] = py;
    float* o_org = out + 16384 + dir * 4096 + kix * 2;
    if (dir == 0) {
      o_org[0] = (meanx + 1.f) * 319.5f;
      o_org[1] = (meany + 1.f) * 239.5f;
    } else {
      o_org[0] = meanx;
      o_org[1] = meany;
    }
    out[28672 + dir * 2048 + kix] = anyv ? 1.f : 0.f;
  }

  // ---- phase 4: window dot-map over 12x10 pixel lattice ----
  const float xfc2 = (ccx + 1.f) * 39.5f;
  const float yfc2 = (ccy + 1.f) * 29.5f;
  const int xb = (int)floorf(xfc2 - 4.9375f);   // 0.125*39.5
  const int yb = (int)floorf(yfc2 - 3.6875f);   // 0.125*29.5
  {
    int pix = tid >> 1;
    int hlf = tid & 1;
    if (pix < NLAT) {
      int lx = pix % LCX, ly = pix / LCX;
      int xi2 = xb + lx, yi2 = yb + ly;
      bool inb2 = (xi2 <= WFm - 1) && (yi2 <= HFm - 1);
      int  p2   = yi2 * WFm + xi2;
      float dacc = 0.f;
      if (inb2) {
        const float4* mp = reinterpret_cast<const float4*>(tgtT + tb + (size_t)p2 * D) + hlf * 16;
        const float4* fS = reinterpret_cast<const float4*>(featSh) + hlf * 16;
#pragma unroll 8
        for (int c = 0; c < 16; ++c) {
          float4 f = fS[c];
          float4 m = mp[c];
          dacc += f.x * m.x + f.y * m.y + f.z * m.z + f.w * m.w;
        }
      }
      float dtot = dacc + __shfl_xor(dacc, 1, 64);
      if (hlf == 0) dm[pix] = inb2 ? tsc[b * NPIX + p2] * dtot : 0.f;
    }
  }
  __syncthreads();

  // ---- phase 5: window samples (thread-per-sample) + softmax/mean/std ----
  const float step = 0.25f / 15.f;
  const float ox = -0.125f + step * (float)(tid & 15);
  const float oy = -0.125f + step * (float)(tid >> 4);
  const float kcx = ccx + ox;
  const float kcy = ccy + oy;
  const float xfw = xfc2 + ox * 39.5f;
  const float yfw = yfc2 + oy * 29.5f;
  const float xw0 = floorf(xfw), yw0 = floorf(yfw);
  const int ix = (int)xw0 - xb;
  const int iy = (int)yw0 - yb;
  const float wxx1 = xfw - xw0, wxx0 = 1.f - wxx1;
  const float wyy1 = yfw - yw0, wyy0 = 1.f - wyy1;
  const int i00 = iy * LCX + ix;
  const float c00 = dm[i00], c10 = dm[i00 + 1];
  const float c01 = dm[i00 + LCX], c11 = dm[i00 + LCX + 1];
  const float corr2 = wxx0 * wyy0 * c00 + wxx1 * wyy0 * c10 +
                      wxx0 * wyy1 * c01 + wxx1 * wyy1 * c11;

  float mx2w = wmax(corr2);
  if (lane == 0) pM2[wid] = mx2w;
  __syncthreads();
  const float mx2 = fmaxf(fmaxf(pM2[0], pM2[1]), fmaxf(pM2[2], pM2[3]));
  const float e2 = expf(corr2 - mx2);
  float t0 = wsum(e2);
  float t1 = wsum(e2 * kcx);
  float t2 = wsum(e2 * kcy);
  float t3 = wsum(e2 * kcx * kcx);
  float t4 = wsum(e2 * kcy * kcy);
  if (lane == 0) {
    pS2[0][wid] = t0; pS2[1][wid] = t1; pS2[2][wid] = t2;
    pS2[3][wid] = t3; pS2[4][wid] = t4;
  }
  __syncthreads();
  if (tid == 0) {
    float sE  = pS2[0][0] + pS2[0][1] + pS2[0][2] + pS2[0][3];
    float mwx = (pS2[1][0] + pS2[1][1] + pS2[1][2] + pS2[1][3]) / sE;
    float mwy = (pS2[2][0] + pS2[2][1] + pS2[2][2] + pS2[2][3]) / sE;
    float qx  = (pS2[3][0] + pS2[3][1] + pS2[3][2] + pS2[3][3]) / sE;
    float qy  = (pS2[4][0] + pS2[4][1] + pS2[4][2] + pS2[4][3]) / sE;
    float vx  = fmaxf(qx - mwx * mwx, 0.f);
    float vy  = fmaxf(qy - mwy * mwy, 0.f);
    float stdv = sqrtf(vx + vy + 1e-12f);
    float* o_w = out + 8192 + dir * 4096 + kix * 2;
    o_w[0] = (mwx + 1.f) * 319.5f;
    o_w[1] = (mwy + 1.f) * 239.5f;
    out[24576 + dir * 2048 + kix] = stdv;
  }
}

}  // namespace

extern "C" void kernel_launch(void* const* d_in, const int* in_sizes, int n_in,
                              void* d_out, int out_size, void* d_ws, size_t ws_size,
                              hipStream_t stream) {
  (void)in_sizes; (void)n_in; (void)out_size; (void)ws_size;
  const float* xf1 = (const float*)d_in[0];
  const float* xf2 = (const float*)d_in[1];
  const float* F1  = (const float*)d_in[2];
  const float* F2  = (const float*)d_in[3];
  const float* c1n = (const float*)d_in[4];
  const float* c2n = (const float*)d_in[5];
  const int* epoch = (const int*)d_in[6];

  float* ws   = (float*)d_ws;
  float* xf1T = ws;
  float* xf2T = ws + (size_t)2 * NPIX * D;
  float* sc1  = ws + (size_t)4 * NPIX * D;
  float* sc2  = sc1 + 2 * NPIX;
  float* out  = (float*)d_out;

  hipLaunchKernelGGL(prep_kernel, dim3(300), dim3(256), 0, stream,
                     xf1, xf2, epoch, xf1T, xf2T, sc1, sc2);
  hipLaunchKernelGGL(line2win_kernel, dim3(4096), dim3(256), 0, stream,
                     xf1T, xf2T, sc1, sc2, F1, F2, c1n, c2n, out);
}

// Round 3
// 79.285 us; speedup vs baseline: 3.7995x; 1.1372x over previous
//
#include <hip/hip_runtime.h>

namespace {

constexpr int D    = 128;   // feature dim
constexpr int WFm  = 80;    // feature map width
constexpr int HFm  = 60;    // feature map height
constexpr int NPIX = WFm * HFm;
constexpr int NKPT = 1024;
constexpr int LCX  = 12;    // window lattice cols
constexpr int LCY  = 10;    // window lattice rows
constexpr int NLAT = LCX * LCY;

__device__ __forceinline__ float wsum(float v) {
#pragma unroll
  for (int m = 32; m; m >>= 1) v += __shfl_xor(v, m, 64);
  return v;
}
__device__ __forceinline__ float wmax(float v) {
#pragma unroll
  for (int m = 32; m; m >>= 1) v = fmaxf(v, __shfl_xor(v, m, 64));
  return v;
}

// ---------------------------------------------------------------------------
// prep: xfT[b][pix][d] = s[pix] * xf[b][d][pix]  (pixel-major, pre-scaled)
//       sc[b][pix]     = s[pix] = T / max(||xf[:,pix]||, 1e-12)
// ---------------------------------------------------------------------------
__global__ __launch_bounds__(256) void prep_kernel(
    const float* __restrict__ xf1, const float* __restrict__ xf2,
    const int* __restrict__ epoch,
    float* __restrict__ xf1T, float* __restrict__ xf2T,
    float* __restrict__ sc1, float* __restrict__ sc2) {
  __shared__ float tile[64 * 129];
  __shared__ float sSh[64];

  const int bi   = blockIdx.x;
  const int img  = bi / 150;
  const int rem  = bi % 150;
  const int b    = rem / 75;
  const int p0   = (rem % 75) * 64;
  const int tid  = threadIdx.x;

  const float* src  = img ? xf2 : xf1;
  float* dstT       = img ? xf2T : xf1T;
  float* dstS       = img ? sc2 : sc1;
  const float T     = fminf(1.0f + (float)(*epoch), 50.0f);

  const int dc = tid >> 6;
  const int px = tid & 63;
#pragma unroll 4
  for (int it = 0; it < 32; ++it) {
    int d = it * 4 + dc;
    tile[px * 129 + d] = src[((size_t)(b * D + d)) * NPIX + p0 + px];
  }
  __syncthreads();

  if (tid < 64) {
    float s = 0.f;
#pragma unroll 8
    for (int d = 0; d < D; ++d) {
      float v = tile[tid * 129 + d];
      s += v * v;
    }
    float sv = T / fmaxf(sqrtf(s), 1e-12f);
    dstS[b * NPIX + p0 + tid] = sv;
    sSh[tid] = sv;
  }
  __syncthreads();

#pragma unroll 4
  for (int it = 0; it < 32; ++it) {
    int idx = it * 256 + tid;
    int lpx = idx >> 7;
    int d   = idx & 127;
    dstT[((size_t)(b * NPIX + p0 + lpx)) * D + d] = tile[lpx * 129 + d] * sSh[lpx];
  }
}

// ---------------------------------------------------------------------------
// main: one block per (dir, b, n). 256 threads = 4 waves.
// ---------------------------------------------------------------------------
__global__ __launch_bounds__(256) void line2win_kernel(
    const float* __restrict__ xf1T, const float* __restrict__ xf2T,
    const float* __restrict__ sc1, const float* __restrict__ sc2,
    const float* __restrict__ F1, const float* __restrict__ F2,
    const float* __restrict__ c1n, const float* __restrict__ c2n,
    float* __restrict__ out) {
  __shared__ __align__(16) float featSh[D];
  __shared__ float corrSh[128];
  __shared__ float dm[NLAT];
  __shared__ float pN[4], pM1[4], pS1[4][4], pM2[4], pS2[5][4];

  const int tid  = threadIdx.x;
  const int lane = tid & 63;
  const int wid  = tid >> 6;
  const int bid  = blockIdx.x;
  const int dir  = bid >> 11;
  const int b    = (bid >> 10) & 1;
  const int n    = bid & 1023;
  const int kix  = b * NKPT + n;

  const float* srcT = dir ? xf2T : xf1T;  // descriptor source (pre-scaled)
  const float* ssc  = dir ? sc2 : sc1;    // source scale (to undo)
  const float* tgtT = dir ? xf1T : xf2T;  // correlation target (pre-scaled)
  const float* Fm   = (dir ? F2 : F1) + b * 9;
  const float* cn   = (dir ? c2n : c1n) + kix * 2;

  const float cnx_in = cn[0], cny_in = cn[1];
  const float px = (cnx_in + 1.f) * 319.5f;
  const float py = (cny_in + 1.f) * 239.5f;

  const float la = Fm[0] * px + Fm[1] * py + Fm[2];
  const float lb = Fm[3] * px + Fm[4] * py + Fm[5];
  const float lc = Fm[6] * px + Fm[7] * py + Fm[8];
  const float eps = 1e-8f;
  const bool  use_x = fabsf(lb) >= fabsf(la);
  const float bden  = (fabsf(lb) < eps) ? eps : lb;
  const float aden  = (fabsf(la) < eps) ? eps : la;
  const bool  degen = (fabsf(la) < eps) && (fabsf(lb) < eps);

  const size_t tb = (size_t)b * NPIX * D;

  // ---- phase 1: descriptor = l2norm(bilinear of RAW src map) ----
  // raw[p] = scaled[p] / s[p]  ->  weight_c' = w_c / s[p_c]
  float fval = 0.f;
  {
    float xf = (cnx_in + 1.f) * 39.5f;
    float yf = (cny_in + 1.f) * 29.5f;
    float x0 = floorf(xf), y0 = floorf(yf);
    float wx1 = xf - x0, wx0 = 1.f - wx1;
    float wy1 = yf - y0, wy0 = 1.f - wy1;
    if (tid < D) {
#pragma unroll
      for (int cyi = 0; cyi < 2; ++cyi)
#pragma unroll
        for (int cxi = 0; cxi < 2; ++cxi) {
          float xi = x0 + (float)cxi, yi = y0 + (float)cyi;
          bool inb = (xi >= 0.f) && (xi <= (float)(WFm - 1)) &&
                     (yi >= 0.f) && (yi <= (float)(HFm - 1));
          float w = (cxi ? wx1 : wx0) * (cyi ? wy1 : wy0);
          if (inb && w != 0.f) {
            int p = (int)yi * WFm + (int)xi;
            fval += (w / ssc[b * NPIX + p]) * srcT[tb + (size_t)p * D + tid];
          }
        }
    }
  }
  float nv = (tid < D) ? fval * fval : 0.f;
  nv = wsum(nv);
  if (lane == 0) pN[wid] = nv;
  __syncthreads();
  const float inv = 1.f / fmaxf(sqrtf(pN[0] + pN[1] + pN[2] + pN[3]), 1e-12f);
  if (tid < D) featSh[tid] = fval * inv;
  __syncthreads();

  const float4* fS = reinterpret_cast<const float4*>(featSh);

  // ---- phase 2: epipolar — 8 lanes per (sample, y-row), coalesced ----
  // lane decomposition: s = lane&7 (byte chunk), yhalf = (lane>>3)&1,
  // sample-in-wave = lane>>4 (0..3); j = it*16 + wid*4 + sample.
  {
    const int s     = lane & 7;
    const int yhalf = (lane >> 3) & 1;
#pragma unroll 2
    for (int it = 0; it < 8; ++it) {
      const int j = it * 16 + wid * 4 + (lane >> 4);
      float tpar = (float)j / 127.0f;
      float xs, ys;
      if (use_x) { xs = tpar * 639.f; ys = -(la * xs + lc) / bden; }
      else       { ys = tpar * 479.f; xs = -(lb * ys + lc) / aden; }
      float xff = fminf(fmaxf((xs / 319.5f) * 39.5f, -4.f), 84.f);
      float yff = fminf(fmaxf((ys / 239.5f) * 29.5f, -4.f), 64.f);
      float x0f = floorf(xff), y0f = floorf(yff);
      int  x0i = (int)x0f, y0i = (int)y0f;
      float wx1 = xff - x0f, wx0 = 1.f - wx1;
      float wy1 = yff - y0f;
      float wyh = yhalf ? wy1 : (1.f - wy1);
      int  yi  = y0i + yhalf;
      bool yin = (yi >= 0) && (yi <= HFm - 1);
      int  yc  = min(max(yi, 0), HFm - 1);
      int  xLow = min(max(x0i, 0), WFm - 2);
      float cL = (xLow == x0i) ? wx0 : ((xLow == x0i + 1) ? wx1 : 0.f);
      float cH = (xLow + 1 == x0i) ? wx0 : ((xLow + 1 == x0i + 1) ? wx1 : 0.f);
      float ymul = yin ? wyh : 0.f;
      cL *= ymul; cH *= ymul;

      float accL = 0.f, accH = 0.f;
      if (cL != 0.f || cH != 0.f) {
        const float4* rowp =
            reinterpret_cast<const float4*>(tgtT + tb + (size_t)(yc * WFm + xLow) * D);
#pragma unroll
        for (int c = 0; c < 4; ++c) {
          float4 f  = fS[c * 8 + s];
          float4 mL = rowp[c * 8 + s];
          float4 mH = rowp[32 + c * 8 + s];
          accL += f.x * mL.x + f.y * mL.y + f.z * mL.z + f.w * mL.w;
          accH += f.x * mH.x + f.y * mH.y + f.z * mH.z + f.w * mH.w;
        }
      }
      float part = cL * accL + cH * accH;
      part += __shfl_xor(part, 1, 64);
      part += __shfl_xor(part, 2, 64);
      part += __shfl_xor(part, 4, 64);
      part += __shfl_xor(part, 8, 64);   // merge the two y-rows
      if ((lane & 15) == 0) corrSh[j] = part;
    }
  }
  __syncthreads();

  // ---- phase 3: masked softmax over L=128 (threads 0..127) ----
  float lgt = -3.0e38f, cxj = 0.f, cyj = 0.f, vj = 0.f;
  if (tid < 128) {
    float tpar = (float)tid / 127.0f;
    float xs, ys;
    if (use_x) { xs = tpar * 639.f; ys = -(la * xs + lc) / bden; }
    else       { ys = tpar * 479.f; xs = -(lb * ys + lc) / aden; }
    bool valid = (xs >= 0.f) && (xs <= 639.f) && (ys >= 0.f) && (ys <= 479.f) && !degen;
    cxj = xs / 319.5f - 1.f;
    cyj = ys / 239.5f - 1.f;
    vj  = valid ? 1.f : 0.f;
    lgt = valid ? corrSh[tid] : -1e9f;
  }
  float mxw = wmax(lgt);
  if (lane == 0) pM1[wid] = mxw;
  __syncthreads();
  const float mx = fmaxf(fmaxf(pM1[0], pM1[1]), fmaxf(pM1[2], pM1[3]));
  const float e  = (tid < 128) ? expf(lgt - mx) : 0.f;
  float s0 = wsum(e);
  float s1 = wsum(e * cxj);
  float s2 = wsum(e * cyj);
  float s3 = wsum(vj);
  if (lane == 0) { pS1[0][wid] = s0; pS1[1][wid] = s1; pS1[2][wid] = s2; pS1[3][wid] = s3; }
  __syncthreads();
  const float sumE = pS1[0][0] + pS1[0][1] + pS1[0][2] + pS1[0][3];
  const float sumX = pS1[1][0] + pS1[1][1] + pS1[1][2] + pS1[1][3];
  const float sumY = pS1[2][0] + pS1[2][1] + pS1[2][2] + pS1[2][3];
  const float sumV = pS1[3][0] + pS1[3][1] + pS1[3][2] + pS1[3][3];
  const float meanx = sumX / sumE;
  const float meany = sumY / sumE;
  const bool  anyv  = sumV > 0.f;
  const float ccx = fminf(fmaxf(meanx, -0.875f), 0.875f);
  const float ccy = fminf(fmaxf(meany, -0.875f), 0.875f);

  if (tid == 0) {
    float* o_coord = out + dir * 4096 + kix * 2;
    o_coord[0] = px;
    o_coord[1] = py;
    float* o_org = out + 16384 + dir * 4096 + kix * 2;
    if (dir == 0) {
      o_org[0] = (meanx + 1.f) * 319.5f;
      o_org[1] = (meany + 1.f) * 239.5f;
    } else {
      o_org[0] = meanx;
      o_org[1] = meany;
    }
    out[28672 + dir * 2048 + kix] = anyv ? 1.f : 0.f;
  }

  // ---- phase 4: window dot-map, row-contiguous coalesced loads ----
  const float xfc2 = (ccx + 1.f) * 39.5f;
  const float yfc2 = (ccy + 1.f) * 29.5f;
  const int xb = (int)floorf(xfc2 - 4.9375f);   // >= 0
  const int yb = (int)floorf(yfc2 - 3.6875f);   // >= 0
  {
    float4 fw = fS[lane & 31];
    for (int lrow = wid; lrow < LCY; lrow += 4) {
      int yi2 = yb + lrow;
      bool yok = (yi2 <= HFm - 1);
      const float4* rp =
          reinterpret_cast<const float4*>(tgtT + tb + (size_t)(yi2 * WFm + xb) * D);
#pragma unroll
      for (int i = 0; i < 6; ++i) {
        int pp  = i * 2 + (lane >> 5);
        int xi2 = xb + pp;
        bool ok = yok && (xi2 <= WFm - 1);
        float v = 0.f;
        if (ok) {
          float4 m = rp[i * 64 + lane];
          v = fw.x * m.x + fw.y * m.y + fw.z * m.z + fw.w * m.w;
        }
        v += __shfl_xor(v, 1, 64);
        v += __shfl_xor(v, 2, 64);
        v += __shfl_xor(v, 4, 64);
        v += __shfl_xor(v, 8, 64);
        v += __shfl_xor(v, 16, 64);
        if ((lane & 31) == 0) dm[lrow * LCX + pp] = ok ? v : 0.f;
      }
    }
  }
  __syncthreads();

  // ---- phase 5: 256 window samples, softmax + mean + std ----
  const float step = 0.25f / 15.f;
  const float ox = -0.125f + step * (float)(tid & 15);
  const float oy = -0.125f + step * (float)(tid >> 4);
  const float kcx = ccx + ox;
  const float kcy = ccy + oy;
  const float xfw = xfc2 + ox * 39.5f;
  const float yfw = yfc2 + oy * 29.5f;
  const float xw0 = floorf(xfw), yw0 = floorf(yfw);
  const int ix = (int)xw0 - xb;
  const int iy = (int)yw0 - yb;
  const float wxx1 = xfw - xw0, wxx0 = 1.f - wxx1;
  const float wyy1 = yfw - yw0, wyy0 = 1.f - wyy1;
  const int i00 = iy * LCX + ix;
  const float c00 = dm[i00], c10 = dm[i00 + 1];
  const float c01 = dm[i00 + LCX], c11 = dm[i00 + LCX + 1];
  const float corr2 = wxx0 * wyy0 * c00 + wxx1 * wyy0 * c10 +
                      wxx0 * wyy1 * c01 + wxx1 * wyy1 * c11;

  float mx2w = wmax(corr2);
  if (lane == 0) pM2[wid] = mx2w;
  __syncthreads();
  const float mx2 = fmaxf(fmaxf(pM2[0], pM2[1]), fmaxf(pM2[2], pM2[3]));
  const float e2 = expf(corr2 - mx2);
  float t0 = wsum(e2);
  float t1 = wsum(e2 * kcx);
  float t2 = wsum(e2 * kcy);
  float t3 = wsum(e2 * kcx * kcx);
  float t4 = wsum(e2 * kcy * kcy);
  if (lane == 0) {
    pS2[0][wid] = t0; pS2[1][wid] = t1; pS2[2][wid] = t2;
    pS2[3][wid] = t3; pS2[4][wid] = t4;
  }
  __syncthreads();
  if (tid == 0) {
    float sE  = pS2[0][0] + pS2[0][1] + pS2[0][2] + pS2[0][3];
    float mwx = (pS2[1][0] + pS2[1][1] + pS2[1][2] + pS2[1][3]) / sE;
    float mwy = (pS2[2][0] + pS2[2][1] + pS2[2][2] + pS2[2][3]) / sE;
    float qx  = (pS2[3][0] + pS2[3][1] + pS2[3][2] + pS2[3][3]) / sE;
    float qy  = (pS2[4][0] + pS2[4][1] + pS2[4][2] + pS2[4][3]) / sE;
    float vx  = fmaxf(qx - mwx * mwx, 0.f);
    float vy  = fmaxf(qy - mwy * mwy, 0.f);
    float stdv = sqrtf(vx + vy + 1e-12f);
    float* o_w = out + 8192 + dir * 4096 + kix * 2;
    o_w[0] = (mwx + 1.f) * 319.5f;
    o_w[1] = (mwy + 1.f) * 239.5f;
    out[24576 + dir * 2048 + kix] = stdv;
  }
}

}  // namespace

extern "C" void kernel_launch(void* const* d_in, const int* in_sizes, int n_in,
                              void* d_out, int out_size, void* d_ws, size_t ws_size,
                              hipStream_t stream) {
  (void)in_sizes; (void)n_in; (void)out_size; (void)ws_size;
  const float* xf1 = (const float*)d_in[0];
  const float* xf2 = (const float*)d_in[1];
  const float* F1  = (const float*)d_in[2];
  const float* F2  = (const float*)d_in[3];
  const float* c1n = (const float*)d_in[4];
  const float* c2n = (const float*)d_in[5];
  const int* epoch = (const int*)d_in[6];

  float* ws   = (float*)d_ws;
  float* xf1T = ws;
  float* xf2T = ws + (size_t)2 * NPIX * D;
  float* sc1  = ws + (size_t)4 * NPIX * D;
  float* sc2  = sc1 + 2 * NPIX;
  float* out  = (float*)d_out;

  hipLaunchKernelGGL(prep_kernel, dim3(300), dim3(256), 0, stream,
                     xf1, xf2, epoch, xf1T, xf2T, sc1, sc2);
  hipLaunchKernelGGL(line2win_kernel, dim3(4096), dim3(256), 0, stream,
                     xf1T, xf2T, sc1, sc2, F1, F2, c1n, c2n, out);
}

// Round 4
// 50.399 us; speedup vs baseline: 5.9772x; 1.5731x over previous
//
#include <hip/hip_runtime.h>
#include <stdint.h>

namespace {

typedef _Float16 half_t;
typedef _Float16 half2_t __attribute__((ext_vector_type(2)));

constexpr int D    = 128;   // feature dim
constexpr int WFm  = 80;    // feature map width
constexpr int HFm  = 60;    // feature map height
constexpr int NPIX = WFm * HFm;
constexpr int NKPT = 1024;
constexpr int LCX  = 12;    // window lattice cols
constexpr int LCY  = 10;    // window lattice rows
constexpr int NLAT = LCX * LCY;

__device__ __forceinline__ float wsum(float v) {
#pragma unroll
  for (int m = 32; m; m >>= 1) v += __shfl_xor(v, m, 64);
  return v;
}
__device__ __forceinline__ float wmax(float v) {
#pragma unroll
  for (int m = 32; m; m >>= 1) v = fmaxf(v, __shfl_xor(v, m, 64));
  return v;
}

__device__ __forceinline__ float dot2acc(uint32_t m, uint32_t f, float acc) {
#if defined(__has_builtin) && __has_builtin(__builtin_amdgcn_fdot2)
  return __builtin_amdgcn_fdot2(__builtin_bit_cast(half2_t, m),
                                __builtin_bit_cast(half2_t, f), acc, false);
#else
  half2_t a = __builtin_bit_cast(half2_t, m);
  half2_t b = __builtin_bit_cast(half2_t, f);
  return acc + (float)a.x * (float)b.x + (float)a.y * (float)b.y;
#endif
}
__device__ __forceinline__ float dot4x2(uint4 m, uint4 f, float acc) {
  acc = dot2acc(m.x, f.x, acc);
  acc = dot2acc(m.y, f.y, acc);
  acc = dot2acc(m.z, f.z, acc);
  acc = dot2acc(m.w, f.w, acc);
  return acc;
}

// ---------------------------------------------------------------------------
// prep: xfH[b][pix][d] = fp16( s[pix] * xf[b][d][pix] )   (pixel-major, = fm)
//       sc[b][pix]     = s[pix] = T / max(||xf[:,pix]||, 1e-12)
// ---------------------------------------------------------------------------
__global__ __launch_bounds__(256) void prep_kernel(
    const float* __restrict__ xf1, const float* __restrict__ xf2,
    const int* __restrict__ epoch,
    half_t* __restrict__ xf1H, half_t* __restrict__ xf2H,
    float* __restrict__ sc1, float* __restrict__ sc2) {
  __shared__ float tile[64 * 129];
  __shared__ float sSh[64];

  const int bi   = blockIdx.x;
  const int img  = bi / 150;
  const int rem  = bi % 150;
  const int b    = rem / 75;
  const int p0   = (rem % 75) * 64;
  const int tid  = threadIdx.x;

  const float* src  = img ? xf2 : xf1;
  half_t* dstH      = img ? xf2H : xf1H;
  float* dstS       = img ? sc2 : sc1;
  const float T     = fminf(1.0f + (float)(*epoch), 50.0f);

  const int dc = tid >> 6;
  const int px = tid & 63;
#pragma unroll 4
  for (int it = 0; it < 32; ++it) {
    int d = it * 4 + dc;
    tile[px * 129 + d] = src[((size_t)(b * D + d)) * NPIX + p0 + px];
  }
  __syncthreads();

  if (tid < 64) {
    float s = 0.f;
#pragma unroll 8
    for (int d = 0; d < D; ++d) {
      float v = tile[tid * 129 + d];
      s += v * v;
    }
    float sv = T / fmaxf(sqrtf(s), 1e-12f);
    dstS[b * NPIX + p0 + tid] = sv;
    sSh[tid] = sv;
  }
  __syncthreads();

#pragma unroll 4
  for (int it = 0; it < 16; ++it) {
    int idx = it * 256 + tid;       // pair index, 0..4095
    int lpx = idx >> 6;             // 0..63
    int dp  = idx & 63;             // 0..63
    float s = sSh[lpx];
    half2_t hv;
    hv.x = (half_t)(tile[lpx * 129 + 2 * dp] * s);
    hv.y = (half_t)(tile[lpx * 129 + 2 * dp + 1] * s);
    *reinterpret_cast<half2_t*>(dstH + ((size_t)(b * NPIX + p0 + lpx)) * D + 2 * dp) = hv;
  }
}

// ---------------------------------------------------------------------------
// main: one block per (dir, b, n). 256 threads = 4 waves.
// ---------------------------------------------------------------------------
__global__ __launch_bounds__(256) void line2win_kernel(
    const half_t* __restrict__ xf1H, const half_t* __restrict__ xf2H,
    const float* __restrict__ sc1, const float* __restrict__ sc2,
    const float* __restrict__ F1, const float* __restrict__ F2,
    const float* __restrict__ c1n, const float* __restrict__ c2n,
    float* __restrict__ out) {
  __shared__ __align__(16) half_t featH[D];
  __shared__ float corrSh[128];
  __shared__ float dm[NLAT];
  __shared__ float pN[4], pM1[4], pS1[4][4], pM2[4], pS2[5][4];

  const int tid  = threadIdx.x;
  const int lane = tid & 63;
  const int wid  = tid >> 6;
  const int bid  = blockIdx.x;
  const int dir  = bid >> 11;
  const int b    = (bid >> 10) & 1;
  const int n    = bid & 1023;
  const int kix  = b * NKPT + n;

  const half_t* srcH = dir ? xf2H : xf1H;  // descriptor source (pre-scaled fm)
  const float*  ssc  = dir ? sc2 : sc1;    // source scale (to undo)
  const half_t* tgtH = dir ? xf1H : xf2H;  // correlation target (pre-scaled fm)
  const float*  Fm   = (dir ? F2 : F1) + b * 9;
  const float*  cn   = (dir ? c2n : c1n) + kix * 2;

  const float cnx_in = cn[0], cny_in = cn[1];
  const float px = (cnx_in + 1.f) * 319.5f;
  const float py = (cny_in + 1.f) * 239.5f;

  const float la = Fm[0] * px + Fm[1] * py + Fm[2];
  const float lb = Fm[3] * px + Fm[4] * py + Fm[5];
  const float lc = Fm[6] * px + Fm[7] * py + Fm[8];
  const float eps = 1e-8f;
  const bool  use_x = fabsf(lb) >= fabsf(la);
  const float bden  = (fabsf(lb) < eps) ? eps : lb;
  const float aden  = (fabsf(la) < eps) ? eps : la;
  const float rdenom = 1.f / (use_x ? bden : aden);
  const bool  degen = (fabsf(la) < eps) && (fabsf(lb) < eps);

  const size_t tb = (size_t)b * NPIX * D;

  // ---- phase 1: descriptor = l2norm(bilinear of RAW src map) ----
  float fval = 0.f;
  {
    float xf = (cnx_in + 1.f) * 39.5f;
    float yf = (cny_in + 1.f) * 29.5f;
    float x0 = floorf(xf), y0 = floorf(yf);
    float wx1 = xf - x0, wx0 = 1.f - wx1;
    float wy1 = yf - y0, wy0 = 1.f - wy1;
    if (tid < D) {
#pragma unroll
      for (int cyi = 0; cyi < 2; ++cyi)
#pragma unroll
        for (int cxi = 0; cxi < 2; ++cxi) {
          float xi = x0 + (float)cxi, yi = y0 + (float)cyi;
          bool inb = (xi >= 0.f) && (xi <= (float)(WFm - 1)) &&
                     (yi >= 0.f) && (yi <= (float)(HFm - 1));
          float w = (cxi ? wx1 : wx0) * (cyi ? wy1 : wy0);
          if (inb && w != 0.f) {
            int p = (int)yi * WFm + (int)xi;
            fval += (w / ssc[b * NPIX + p]) * (float)srcH[tb + (size_t)p * D + tid];
          }
        }
    }
  }
  float nv = (tid < D) ? fval * fval : 0.f;
  nv = wsum(nv);
  if (lane == 0) pN[wid] = nv;
  __syncthreads();
  const float inv = 1.f / fmaxf(sqrtf(pN[0] + pN[1] + pN[2] + pN[3]), 1e-12f);
  if (tid < D) featH[tid] = (half_t)(fval * inv);
  __syncthreads();

  const uint4* fH4 = reinterpret_cast<const uint4*>(featH);

  // ---- phase 2: epipolar — 8 lanes per (sample, y-row), f16 dot2 ----
  {
    const int s     = lane & 7;
    const int yhalf = (lane >> 3) & 1;
    const uint4 fL0 = fH4[s];
    const uint4 fL1 = fH4[8 + s];
#pragma unroll 2
    for (int it = 0; it < 8; ++it) {
      const int j = it * 16 + wid * 4 + (lane >> 4);
      float tpar = (float)j / 127.0f;
      float xs, ys;
      if (use_x) { xs = tpar * 639.f; ys = -fmaf(la, xs, lc) * rdenom; }
      else       { ys = tpar * 479.f; xs = -fmaf(lb, ys, lc) * rdenom; }
      float xff = fminf(fmaxf(xs * (39.5f / 319.5f), -4.f), 84.f);
      float yff = fminf(fmaxf(ys * (29.5f / 239.5f), -4.f), 64.f);
      float x0f = floorf(xff), y0f = floorf(yff);
      int  x0i = (int)x0f, y0i = (int)y0f;
      float wx1 = xff - x0f, wx0 = 1.f - wx1;
      float wy1 = yff - y0f;
      float wyh = yhalf ? wy1 : (1.f - wy1);
      int  yi  = y0i + yhalf;
      bool yin = (yi >= 0) && (yi <= HFm - 1);
      int  yc  = min(max(yi, 0), HFm - 1);
      int  xLow = min(max(x0i, 0), WFm - 2);
      float cL = (xLow == x0i) ? wx0 : ((xLow == x0i + 1) ? wx1 : 0.f);
      float cH = (xLow + 1 == x0i) ? wx0 : ((xLow + 1 == x0i + 1) ? wx1 : 0.f);
      float ymul = yin ? wyh : 0.f;
      cL *= ymul; cH *= ymul;

      float accL = 0.f, accH = 0.f;
      if (cL != 0.f || cH != 0.f) {
        const uint4* rowp =
            reinterpret_cast<const uint4*>(tgtH + tb + (size_t)(yc * WFm + xLow) * D);
        uint4 mL0 = rowp[s];
        uint4 mL1 = rowp[8 + s];
        uint4 mH0 = rowp[16 + s];
        uint4 mH1 = rowp[24 + s];
        accL = dot4x2(mL0, fL0, accL);
        accL = dot4x2(mL1, fL1, accL);
        accH = dot4x2(mH0, fL0, accH);
        accH = dot4x2(mH1, fL1, accH);
      }
      float part = cL * accL + cH * accH;
      part += __shfl_xor(part, 1, 64);
      part += __shfl_xor(part, 2, 64);
      part += __shfl_xor(part, 4, 64);
      part += __shfl_xor(part, 8, 64);   // merge the two y-rows
      if ((lane & 15) == 0) corrSh[j] = part;
    }
  }
  __syncthreads();

  // ---- phase 3: masked softmax over L=128 (threads 0..127) ----
  float lgt = -3.0e38f, cxj = 0.f, cyj = 0.f, vj = 0.f;
  if (tid < 128) {
    float tpar = (float)tid / 127.0f;
    float xs, ys;
    if (use_x) { xs = tpar * 639.f; ys = -fmaf(la, xs, lc) * rdenom; }
    else       { ys = tpar * 479.f; xs = -fmaf(lb, ys, lc) * rdenom; }
    bool valid = (xs >= 0.f) && (xs <= 639.f) && (ys >= 0.f) && (ys <= 479.f) && !degen;
    cxj = xs / 319.5f - 1.f;
    cyj = ys / 239.5f - 1.f;
    vj  = valid ? 1.f : 0.f;
    lgt = valid ? corrSh[tid] : -1e9f;
  }
  float mxw = wmax(lgt);
  if (lane == 0) pM1[wid] = mxw;
  __syncthreads();
  const float mx = fmaxf(fmaxf(pM1[0], pM1[1]), fmaxf(pM1[2], pM1[3]));
  const float e  = (tid < 128) ? expf(lgt - mx) : 0.f;
  float s0 = wsum(e);
  float s1 = wsum(e * cxj);
  float s2 = wsum(e * cyj);
  float s3 = wsum(vj);
  if (lane == 0) { pS1[0][wid] = s0; pS1[1][wid] = s1; pS1[2][wid] = s2; pS1[3][wid] = s3; }
  __syncthreads();
  const float sumE = pS1[0][0] + pS1[0][1] + pS1[0][2] + pS1[0][3];
  const float sumX = pS1[1][0] + pS1[1][1] + pS1[1][2] + pS1[1][3];
  const float sumY = pS1[2][0] + pS1[2][1] + pS1[2][2] + pS1[2][3];
  const float sumV = pS1[3][0] + pS1[3][1] + pS1[3][2] + pS1[3][3];
  const float meanx = sumX / sumE;
  const float meany = sumY / sumE;
  const bool  anyv  = sumV > 0.f;
  const float ccx = fminf(fmaxf(meanx, -0.875f), 0.875f);
  const float ccy = fminf(fmaxf(meany, -0.875f), 0.875f);

  if (tid == 0) {
    float* o_coord = out + dir * 4096 + kix * 2;
    o_coord[0] = px;
    o_coord[1] = py;
    float* o_org = out + 16384 + dir * 4096 + kix * 2;
    if (dir == 0) {
      o_org[0] = (meanx + 1.f) * 319.5f;
      o_org[1] = (meany + 1.f) * 239.5f;
    } else {
      o_org[0] = meanx;
      o_org[1] = meany;
    }
    out[28672 + dir * 2048 + kix] = anyv ? 1.f : 0.f;
  }

  // ---- phase 4: window dot-map, 16 lanes per pixel, f16 dot2 ----
  const float xfc2 = (ccx + 1.f) * 39.5f;
  const float yfc2 = (ccy + 1.f) * 29.5f;
  const int xb = (int)floorf(xfc2 - 4.9375f);   // >= 0
  const int yb = (int)floorf(yfc2 - 3.6875f);   // >= 0
  {
    const int s4 = lane & 15;
    const int pp = lane >> 4;
    const uint4 fw = fH4[s4];
    for (int lrow = wid; lrow < LCY; lrow += 4) {
      int yi2 = yb + lrow;
      bool yok = (yi2 <= HFm - 1);
      const uint4* rp =
          reinterpret_cast<const uint4*>(tgtH + tb + (size_t)(yi2 * WFm + xb) * D);
#pragma unroll
      for (int i = 0; i < 3; ++i) {
        int pix = i * 4 + pp;                 // 0..11
        int xi2 = xb + pix;
        bool ok = yok && (xi2 <= WFm - 1);
        float v = 0.f;
        if (ok) {
          uint4 m = rp[pix * 16 + s4];
          v = dot4x2(m, fw, 0.f);
        }
        v += __shfl_xor(v, 1, 64);
        v += __shfl_xor(v, 2, 64);
        v += __shfl_xor(v, 4, 64);
        v += __shfl_xor(v, 8, 64);
        if (s4 == 0) dm[lrow * LCX + pix] = ok ? v : 0.f;
      }
    }
  }
  __syncthreads();

  // ---- phase 5: 256 window samples, softmax + mean + std ----
  const float step = 0.25f / 15.f;
  const float ox = -0.125f + step * (float)(tid & 15);
  const float oy = -0.125f + step * (float)(tid >> 4);
  const float kcx = ccx + ox;
  const float kcy = ccy + oy;
  const float xfw = xfc2 + ox * 39.5f;
  const float yfw = yfc2 + oy * 29.5f;
  const float xw0 = floorf(xfw), yw0 = floorf(yfw);
  const int ix = (int)xw0 - xb;
  const int iy = (int)yw0 - yb;
  const float wxx1 = xfw - xw0, wxx0 = 1.f - wxx1;
  const float wyy1 = yfw - yw0, wyy0 = 1.f - wyy1;
  const int i00 = iy * LCX + ix;
  const float c00 = dm[i00], c10 = dm[i00 + 1];
  const float c01 = dm[i00 + LCX], c11 = dm[i00 + LCX + 1];
  const float corr2 = wxx0 * wyy0 * c00 + wxx1 * wyy0 * c10 +
                      wxx0 * wyy1 * c01 + wxx1 * wyy1 * c11;

  float mx2w = wmax(corr2);
  if (lane == 0) pM2[wid] = mx2w;
  __syncthreads();
  const float mx2 = fmaxf(fmaxf(pM2[0], pM2[1]), fmaxf(pM2[2], pM2[3]));
  const float e2 = expf(corr2 - mx2);
  float t0 = wsum(e2);
  float t1 = wsum(e2 * kcx);
  float t2 = wsum(e2 * kcy);
  float t3 = wsum(e2 * kcx * kcx);
  float t4 = wsum(e2 * kcy * kcy);
  if (lane == 0) {
    pS2[0][wid] = t0; pS2[1][wid] = t1; pS2[2][wid] = t2;
    pS2[3][wid] = t3; pS2[4][wid] = t4;
  }
  __syncthreads();
  if (tid == 0) {
    float sE  = pS2[0][0] + pS2[0][1] + pS2[0][2] + pS2[0][3];
    float mwx = (pS2[1][0] + pS2[1][1] + pS2[1][2] + pS2[1][3]) / sE;
    float mwy = (pS2[2][0] + pS2[2][1] + pS2[2][2] + pS2[2][3]) / sE;
    float qx  = (pS2[3][0] + pS2[3][1] + pS2[3][2] + pS2[3][3]) / sE;
    float qy  = (pS2[4][0] + pS2[4][1] + pS2[4][2] + pS2[4][3]) / sE;
    float vx  = fmaxf(qx - mwx * mwx, 0.f);
    float vy  = fmaxf(qy - mwy * mwy, 0.f);
    float stdv = sqrtf(vx + vy + 1e-12f);
    float* o_w = out + 8192 + dir * 4096 + kix * 2;
    o_w[0] = (mwx + 1.f) * 319.5f;
    o_w[1] = (mwy + 1.f) * 239.5f;
    out[24576 + dir * 2048 + kix] = stdv;
  }
}

}  // namespace

extern "C" void kernel_launch(void* const* d_in, const int* in_sizes, int n_in,
                              void* d_out, int out_size, void* d_ws, size_t ws_size,
                              hipStream_t stream) {
  (void)in_sizes; (void)n_in; (void)out_size; (void)ws_size;
  const float* xf1 = (const float*)d_in[0];
  const float* xf2 = (const float*)d_in[1];
  const float* F1  = (const float*)d_in[2];
  const float* F2  = (const float*)d_in[3];
  const float* c1n = (const float*)d_in[4];
  const float* c2n = (const float*)d_in[5];
  const int* epoch = (const int*)d_in[6];

  half_t* xf1H = (half_t*)d_ws;                           // 2*4800*128 halves
  half_t* xf2H = xf1H + (size_t)2 * NPIX * D;             // 2*4800*128 halves
  float*  sc1  = (float*)(xf2H + (size_t)2 * NPIX * D);   // 2*4800 f32
  float*  sc2  = sc1 + 2 * NPIX;                          // 2*4800 f32
  float*  out  = (float*)d_out;

  hipLaunchKernelGGL(prep_kernel, dim3(300), dim3(256), 0, stream,
                     xf1, xf2, epoch, xf1H, xf2H, sc1, sc2);
  hipLaunchKernelGGL(line2win_kernel, dim3(4096), dim3(256), 0, stream,
                     xf1H, xf2H, sc1, sc2, F1, F2, c1n, c2n, out);
}

// Round 5
// 48.186 us; speedup vs baseline: 6.2517x; 1.0459x over previous
//
#include <hip/hip_runtime.h>
#include <stdint.h>

namespace {

typedef _Float16 half_t;
typedef _Float16 half2_t __attribute__((ext_vector_type(2)));

constexpr int D    = 128;   // feature dim
constexpr int WFm  = 80;    // feature map width
constexpr int HFm  = 60;    // feature map height
constexpr int NPIX = WFm * HFm;
constexpr int NKPT = 1024;
constexpr int LCX  = 12;    // window lattice cols
constexpr int LCY  = 10;    // window lattice rows
constexpr int NLAT = LCX * LCY;

__device__ __forceinline__ float wsum(float v) {
#pragma unroll
  for (int m = 32; m; m >>= 1) v += __shfl_xor(v, m, 64);
  return v;
}
__device__ __forceinline__ float wmax(float v) {
#pragma unroll
  for (int m = 32; m; m >>= 1) v = fmaxf(v, __shfl_xor(v, m, 64));
  return v;
}

__device__ __forceinline__ float dot2acc(uint32_t m, uint32_t f, float acc) {
#if defined(__has_builtin) && __has_builtin(__builtin_amdgcn_fdot2)
  return __builtin_amdgcn_fdot2(__builtin_bit_cast(half2_t, m),
                                __builtin_bit_cast(half2_t, f), acc, false);
#else
  half2_t a = __builtin_bit_cast(half2_t, m);
  half2_t b = __builtin_bit_cast(half2_t, f);
  return acc + (float)a.x * (float)b.x + (float)a.y * (float)b.y;
#endif
}
__device__ __forceinline__ float dot4x2(uint4 m, uint4 f, float acc) {
  acc = dot2acc(m.x, f.x, acc);
  acc = dot2acc(m.y, f.y, acc);
  acc = dot2acc(m.z, f.z, acc);
  acc = dot2acc(m.w, f.w, acc);
  return acc;
}

// ---------------------------------------------------------------------------
// prep: xfH[b][pix][d] = fp16( s[pix] * xf[b][d][pix] )   (pixel-major, = fm)
//       sc[b][pix]     = s[pix] = T / max(||xf[:,pix]||, 1e-12)
// ---------------------------------------------------------------------------
__global__ __launch_bounds__(256) void prep_kernel(
    const float* __restrict__ xf1, const float* __restrict__ xf2,
    const int* __restrict__ epoch,
    half_t* __restrict__ xf1H, half_t* __restrict__ xf2H,
    float* __restrict__ sc1, float* __restrict__ sc2) {
  __shared__ float tile[64 * 129];
  __shared__ float qSh[4][64];
  __shared__ float sSh[64];

  const int bi   = blockIdx.x;
  const int img  = bi / 150;
  const int rem  = bi % 150;
  const int b    = rem / 75;
  const int p0   = (rem % 75) * 64;
  const int tid  = threadIdx.x;

  const float* src  = img ? xf2 : xf1;
  half_t* dstH      = img ? xf2H : xf1H;
  float* dstS       = img ? sc2 : sc1;
  const float T     = fminf(1.0f + (float)(*epoch), 50.0f);

  const int dc = tid >> 6;
  const int px = tid & 63;
#pragma unroll 4
  for (int it = 0; it < 32; ++it) {
    int d = it * 4 + dc;
    tile[px * 129 + d] = src[((size_t)(b * D + d)) * NPIX + p0 + px];
  }
  __syncthreads();

  {
    float s = 0.f;
    const int d0 = dc * 32;
#pragma unroll 8
    for (int d = 0; d < 32; ++d) {
      float v = tile[px * 129 + d0 + d];
      s += v * v;
    }
    qSh[dc][px] = s;
  }
  __syncthreads();
  if (tid < 64) {
    float s = qSh[0][tid] + qSh[1][tid] + qSh[2][tid] + qSh[3][tid];
    float sv = T / fmaxf(sqrtf(s), 1e-12f);
    dstS[b * NPIX + p0 + tid] = sv;
    sSh[tid] = sv;
  }
  __syncthreads();

#pragma unroll 4
  for (int it = 0; it < 16; ++it) {
    int idx = it * 256 + tid;       // pair index, 0..4095
    int lpx = idx >> 6;             // 0..63
    int dp  = idx & 63;             // 0..63
    float s = sSh[lpx];
    half2_t hv;
    hv.x = (half_t)(tile[lpx * 129 + 2 * dp] * s);
    hv.y = (half_t)(tile[lpx * 129 + 2 * dp + 1] * s);
    *reinterpret_cast<half2_t*>(dstH + ((size_t)(b * NPIX + p0 + lpx)) * D + 2 * dp) = hv;
  }
}

// ---------------------------------------------------------------------------
// main: one block per (dir, b, n). 256 threads = 4 waves.
// ---------------------------------------------------------------------------
__global__ __launch_bounds__(256) void line2win_kernel(
    const half_t* __restrict__ xf1H, const half_t* __restrict__ xf2H,
    const float* __restrict__ sc1, const float* __restrict__ sc2,
    const float* __restrict__ F1, const float* __restrict__ F2,
    const float* __restrict__ c1n, const float* __restrict__ c2n,
    float* __restrict__ out) {
  __shared__ __align__(16) half_t featH[D];
  __shared__ float4 sPar[2][128];   // {rowBase(int bits), coefL, coefH, -}
  __shared__ float corrSh[128];
  __shared__ float dm[NLAT];
  __shared__ float pN[4], pM1[4], pS1[4][4], pM2[4], pS2[5][4];

  const int tid  = threadIdx.x;
  const int lane = tid & 63;
  const int wid  = tid >> 6;
  const int bid  = blockIdx.x;
  const int dir  = bid >> 11;
  const int b    = (bid >> 10) & 1;
  const int n    = bid & 1023;
  const int kix  = b * NKPT + n;

  const half_t* srcH = dir ? xf2H : xf1H;  // descriptor source (pre-scaled fm)
  const float*  ssc  = dir ? sc2 : sc1;    // source scale (to undo)
  const half_t* tgtH = dir ? xf1H : xf2H;  // correlation target (pre-scaled fm)
  const float*  Fm   = (dir ? F2 : F1) + b * 9;
  const float*  cn   = (dir ? c2n : c1n) + kix * 2;

  const float cnx_in = cn[0], cny_in = cn[1];
  const float px = (cnx_in + 1.f) * 319.5f;
  const float py = (cny_in + 1.f) * 239.5f;

  const float la = Fm[0] * px + Fm[1] * py + Fm[2];
  const float lb = Fm[3] * px + Fm[4] * py + Fm[5];
  const float lc = Fm[6] * px + Fm[7] * py + Fm[8];
  const float eps = 1e-8f;
  const bool  use_x = fabsf(lb) >= fabsf(la);
  const float bden  = (fabsf(lb) < eps) ? eps : lb;
  const float aden  = (fabsf(la) < eps) ? eps : la;
  const float rdenom = 1.f / (use_x ? bden : aden);
  const bool  degen = (fabsf(la) < eps) && (fabsf(lb) < eps);

  const size_t tb = (size_t)b * NPIX * D;

  // ---- phase 1a: descriptor bilinear gather (threads 0..127) ----
  float fval = 0.f;
  {
    float xf = (cnx_in + 1.f) * 39.5f;
    float yf = (cny_in + 1.f) * 29.5f;
    float x0 = floorf(xf), y0 = floorf(yf);
    float wx1 = xf - x0, wx0 = 1.f - wx1;
    float wy1 = yf - y0, wy0 = 1.f - wy1;
    if (tid < D) {
#pragma unroll
      for (int cyi = 0; cyi < 2; ++cyi)
#pragma unroll
        for (int cxi = 0; cxi < 2; ++cxi) {
          float xi = x0 + (float)cxi, yi = y0 + (float)cyi;
          bool inb = (xi >= 0.f) && (xi <= (float)(WFm - 1)) &&
                     (yi >= 0.f) && (yi <= (float)(HFm - 1));
          float w = (cxi ? wx1 : wx0) * (cyi ? wy1 : wy0);
          if (inb && w != 0.f) {
            int p = (int)yi * WFm + (int)xi;
            fval += (w / ssc[b * NPIX + p]) * (float)srcH[tb + (size_t)p * D + tid];
          }
        }
    }
  }

  // ---- phase 1b: per-sample line params into LDS (threads 0..127) ----
  if (tid < 128) {
    float tpar = (float)tid / 127.0f;
    float xs, ys;
    if (use_x) { xs = tpar * 639.f; ys = -fmaf(la, xs, lc) * rdenom; }
    else       { ys = tpar * 479.f; xs = -fmaf(lb, ys, lc) * rdenom; }
    float xff = fminf(fmaxf(xs * (39.5f / 319.5f), -4.f), 84.f);
    float yff = fminf(fmaxf(ys * (29.5f / 239.5f), -4.f), 64.f);
    float x0f = floorf(xff), y0f = floorf(yff);
    int  x0i = (int)x0f, y0i = (int)y0f;
    float wx1 = xff - x0f, wx0 = 1.f - wx1;
    float wy1 = yff - y0f;
    int  xLow = min(max(x0i, 0), WFm - 2);
    float cL0 = (xLow == x0i) ? wx0 : ((xLow == x0i + 1) ? wx1 : 0.f);
    float cH0 = (xLow + 1 == x0i) ? wx0 : ((xLow + 1 == x0i + 1) ? wx1 : 0.f);
#pragma unroll
    for (int h = 0; h < 2; ++h) {
      int yi = y0i + h;
      bool yin = (yi >= 0) && (yi <= HFm - 1);
      int yc = min(max(yi, 0), HFm - 1);
      float wyh = h ? wy1 : (1.f - wy1);
      float ymul = yin ? wyh : 0.f;
      float4 p4;
      p4.x = __int_as_float(yc * WFm + xLow);
      p4.y = cL0 * ymul;
      p4.z = cH0 * ymul;
      p4.w = 0.f;
      sPar[h][tid] = p4;
    }
  }

  // ---- phase 1c: norm reduce + feature store ----
  float nv = (tid < D) ? fval * fval : 0.f;
  nv = wsum(nv);
  if (lane == 0) pN[wid] = nv;
  __syncthreads();
  const float inv = 1.f / fmaxf(sqrtf(pN[0] + pN[1] + pN[2] + pN[3]), 1e-12f);
  if (tid < D) featH[tid] = (half_t)(fval * inv);
  __syncthreads();

  const uint4* fH4 = reinterpret_cast<const uint4*>(featH);

  // ---- phase 2: epipolar gather — 8 lanes per (sample, y-half) ----
  {
    const int s = lane & 7;
    const int h = (lane >> 3) & 1;
    const uint4 fL0 = fH4[s];
    const uint4 fL1 = fH4[8 + s];
#pragma unroll 2
    for (int it = 0; it < 8; ++it) {
      const int j = it * 16 + wid * 4 + (lane >> 4);
      const float4 p4 = sPar[h][j];
      const int   off = __float_as_int(p4.x);
      const float cL  = p4.y;
      const float cH  = p4.z;
      float acc = 0.f;
      if (cL != 0.f || cH != 0.f) {
        const uint4* rowp = reinterpret_cast<const uint4*>(tgtH + tb + (size_t)off * D);
        uint4 mL0 = rowp[s];
        uint4 mL1 = rowp[8 + s];
        uint4 mH0 = rowp[16 + s];
        uint4 mH1 = rowp[24 + s];
        float accL = dot4x2(mL0, fL0, 0.f);
        accL = dot4x2(mL1, fL1, accL);
        float accH = dot4x2(mH0, fL0, 0.f);
        accH = dot4x2(mH1, fL1, accH);
        acc = cL * accL + cH * accH;
      }
      acc += __shfl_xor(acc, 1, 64);
      acc += __shfl_xor(acc, 2, 64);
      acc += __shfl_xor(acc, 4, 64);
      acc += __shfl_xor(acc, 8, 64);   // merge the two y-halves
      if ((lane & 15) == 0) corrSh[j] = acc;
    }
  }
  __syncthreads();

  // ---- phase 3: masked softmax over L=128 (threads 0..127) ----
  float lgt = -3.0e38f, cxj = 0.f, cyj = 0.f, vj = 0.f;
  if (tid < 128) {
    float tpar = (float)tid / 127.0f;
    float xs, ys;
    if (use_x) { xs = tpar * 639.f; ys = -fmaf(la, xs, lc) * rdenom; }
    else       { ys = tpar * 479.f; xs = -fmaf(lb, ys, lc) * rdenom; }
    bool valid = (xs >= 0.f) && (xs <= 639.f) && (ys >= 0.f) && (ys <= 479.f) && !degen;
    cxj = xs / 319.5f - 1.f;
    cyj = ys / 239.5f - 1.f;
    vj  = valid ? 1.f : 0.f;
    lgt = valid ? corrSh[tid] : -1e9f;
  }
  float mxw = wmax(lgt);
  if (lane == 0) pM1[wid] = mxw;
  __syncthreads();
  const float mx = fmaxf(fmaxf(pM1[0], pM1[1]), fmaxf(pM1[2], pM1[3]));
  const float e  = (tid < 128) ? expf(lgt - mx) : 0.f;
  float s0 = wsum(e);
  float s1 = wsum(e * cxj);
  float s2 = wsum(e * cyj);
  float s3 = wsum(vj);
  if (lane == 0) { pS1[0][wid] = s0; pS1[1][wid] = s1; pS1[2][wid] = s2; pS1[3][wid] = s3; }
  __syncthreads();
  const float sumE = pS1[0][0] + pS1[0][1] + pS1[0][2] + pS1[0][3];
  const float sumX = pS1[1][0] + pS1[1][1] + pS1[1][2] + pS1[1][3];
  const float sumY = pS1[2][0] + pS1[2][1] + pS1[2][2] + pS1[2][3];
  const float sumV = pS1[3][0] + pS1[3][1] + pS1[3][2] + pS1[3][3];
  const float meanx = sumX / sumE;
  const float meany = sumY / sumE;
  const bool  anyv  = sumV > 0.f;
  const float ccx = fminf(fmaxf(meanx, -0.875f), 0.875f);
  const float ccy = fminf(fmaxf(meany, -0.875f), 0.875f);

  if (tid == 0) {
    float* o_coord = out + dir * 4096 + kix * 2;
    o_coord[0] = px;
    o_coord[1] = py;
    float* o_org = out + 16384 + dir * 4096 + kix * 2;
    if (dir == 0) {
      o_org[0] = (meanx + 1.f) * 319.5f;
      o_org[1] = (meany + 1.f) * 239.5f;
    } else {
      o_org[0] = meanx;
      o_org[1] = meany;
    }
    out[28672 + dir * 2048 + kix] = anyv ? 1.f : 0.f;
  }

  // ---- phase 4: window dot-map, 16 lanes per pixel, f16 dot2 ----
  const float xfc2 = (ccx + 1.f) * 39.5f;
  const float yfc2 = (ccy + 1.f) * 29.5f;
  const int xb = (int)floorf(xfc2 - 4.9375f);   // >= 0
  const int yb = (int)floorf(yfc2 - 3.6875f);   // >= 0
  {
    const int s4 = lane & 15;
    const int pp = lane >> 4;
    const uint4 fw = fH4[s4];
    for (int lrow = wid; lrow < LCY; lrow += 4) {
      int yi2 = yb + lrow;
      bool yok = (yi2 <= HFm - 1);
      const uint4* rp =
          reinterpret_cast<const uint4*>(tgtH + tb + (size_t)(yi2 * WFm + xb) * D);
#pragma unroll
      for (int i = 0; i < 3; ++i) {
        int pix = i * 4 + pp;                 // 0..11
        int xi2 = xb + pix;
        bool ok = yok && (xi2 <= WFm - 1);
        float v = 0.f;
        if (ok) {
          uint4 m = rp[pix * 16 + s4];
          v = dot4x2(m, fw, 0.f);
        }
        v += __shfl_xor(v, 1, 64);
        v += __shfl_xor(v, 2, 64);
        v += __shfl_xor(v, 4, 64);
        v += __shfl_xor(v, 8, 64);
        if (s4 == 0) dm[lrow * LCX + pix] = ok ? v : 0.f;
      }
    }
  }
  __syncthreads();

  // ---- phase 5: 256 window samples, softmax + mean + std ----
  const float step = 0.25f / 15.f;
  const float ox = -0.125f + step * (float)(tid & 15);
  const float oy = -0.125f + step * (float)(tid >> 4);
  const float kcx = ccx + ox;
  const float kcy = ccy + oy;
  const float xfw = xfc2 + ox * 39.5f;
  const float yfw = yfc2 + oy * 29.5f;
  const float xw0 = floorf(xfw), yw0 = floorf(yfw);
  const int ix = (int)xw0 - xb;
  const int iy = (int)yw0 - yb;
  const float wxx1 = xfw - xw0, wxx0 = 1.f - wxx1;
  const float wyy1 = yfw - yw0, wyy0 = 1.f - wyy1;
  const int i00 = iy * LCX + ix;
  const float c00 = dm[i00], c10 = dm[i00 + 1];
  const float c01 = dm[i00 + LCX], c11 = dm[i00 + LCX + 1];
  const float corr2 = wxx0 * wyy0 * c00 + wxx1 * wyy0 * c10 +
                      wxx0 * wyy1 * c01 + wxx1 * wyy1 * c11;

  float mx2w = wmax(corr2);
  if (lane == 0) pM2[wid] = mx2w;
  __syncthreads();
  const float mx2 = fmaxf(fmaxf(pM2[0], pM2[1]), fmaxf(pM2[2], pM2[3]));
  const float e2 = expf(corr2 - mx2);
  float t0 = wsum(e2);
  float t1 = wsum(e2 * kcx);
  float t2 = wsum(e2 * kcy);
  float t3 = wsum(e2 * kcx * kcx);
  float t4 = wsum(e2 * kcy * kcy);
  if (lane == 0) {
    pS2[0][wid] = t0; pS2[1][wid] = t1; pS2[2][wid] = t2;
    pS2[3][wid] = t3; pS2[4][wid] = t4;
  }
  __syncthreads();
  if (tid == 0) {
    float sE  = pS2[0][0] + pS2[0][1] + pS2[0][2] + pS2[0][3];
    float mwx = (pS2[1][0] + pS2[1][1] + pS2[1][2] + pS2[1][3]) / sE;
    float mwy = (pS2[2][0] + pS2[2][1] + pS2[2][2] + pS2[2][3]) / sE;
    float qx  = (pS2[3][0] + pS2[3][1] + pS2[3][2] + pS2[3][3]) / sE;
    float qy  = (pS2[4][0] + pS2[4][1] + pS2[4][2] + pS2[4][3]) / sE;
    float vx  = fmaxf(qx - mwx * mwx, 0.f);
    float vy  = fmaxf(qy - mwy * mwy, 0.f);
    float stdv = sqrtf(vx + vy + 1e-12f);
    float* o_w = out + 8192 + dir * 4096 + kix * 2;
    o_w[0] = (mwx + 1.f) * 319.5f;
    o_w[1] = (mwy + 1.f) * 239.5f;
    out[24576 + dir * 2048 + kix] = stdv;
  }
}

}  // namespace

extern "C" void kernel_launch(void* const* d_in, const int* in_sizes, int n_in,
                              void* d_out, int out_size, void* d_ws, size_t ws_size,
                              hipStream_t stream) {
  (void)in_sizes; (void)n_in; (void)out_size; (void)ws_size;
  const float* xf1 = (const float*)d_in[0];
  const float* xf2 = (const float*)d_in[1];
  const float* F1  = (const float*)d_in[2];
  const float* F2  = (const float*)d_in[3];
  const float* c1n = (const float*)d_in[4];
  const float* c2n = (const float*)d_in[5];
  const int* epoch = (const int*)d_in[6];

  half_t* xf1H = (half_t*)d_ws;                           // 2*4800*128 halves
  half_t* xf2H = xf1H + (size_t)2 * NPIX * D;             // 2*4800*128 halves
  float*  sc1  = (float*)(xf2H + (size_t)2 * NPIX * D);   // 2*4800 f32
  float*  sc2  = sc1 + 2 * NPIX;                          // 2*4800 f32
  float*  out  = (float*)d_out;

  hipLaunchKernelGGL(prep_kernel, dim3(300), dim3(256), 0, stream,
                     xf1, xf2, epoch, xf1H, xf2H, sc1, sc2);
  hipLaunchKernelGGL(line2win_kernel, dim3(4096), dim3(256), 0, stream,
                     xf1H, xf2H, sc1, sc2, F1, F2, c1n, c2n, out);
}